// Round 3
// baseline (29.151 us; speedup 1.0000x reference)
//
#include <hip/hip_runtime.h>

#define HW 16384      // 128*128
#define NCH 128       // channels
#define CCH 8         // channels per block
#define LANG 256
#define NH 128
#define NOP 6

typedef float f4 __attribute__((ext_vector_type(4)));

// Per-batch coefficients: coefs[b*12 + 0..5] = gamma[b,k]*wr[k],
// coefs[b*12 + 6..11] = beta[b,k]*wr[k]; coefs[48] = sum(wr); coefs[49] = br.
//
// Wave-parallel: 4 blocks (one per batch) x 256 threads (4 waves).
// Stage 1: actv[j] = bs[j] + lang[b,:] . Ws[j,:]  (128 dots of length 256)
//   wave w computes j = w*32+m; lanes hold float4 chunks, butterfly-reduce.
// Stage 2: 12 dots of length 128 (gamma/beta), 3 per wave.
__global__ __launch_bounds__(256) void coef_kernel(
    const float* __restrict__ lang, const float* __restrict__ Ws,
    const float* __restrict__ bs, const float* __restrict__ Wg,
    const float* __restrict__ bg, const float* __restrict__ Wb,
    const float* __restrict__ bb, const float* __restrict__ Wr,
    const float* __restrict__ br, float* __restrict__ coefs) {
  const int b = blockIdx.x;
  const int tid = threadIdx.x;
  const int wave = tid >> 6, lane = tid & 63;
  __shared__ float actv[NH];

  // each lane owns i-range [lane*4, lane*4+4) of the 256-wide inner dim
  const f4 lv = *(const f4*)(lang + b * LANG + lane * 4);

  #pragma unroll 8
  for (int m = 0; m < 32; ++m) {
    const int j = wave * 32 + m;
    const f4 wv = *(const f4*)(Ws + (size_t)j * LANG + lane * 4);
    float p = lv.x * wv.x + lv.y * wv.y + lv.z * wv.z + lv.w * wv.w;
    #pragma unroll
    for (int off = 32; off; off >>= 1) p += __shfl_xor(p, off);
    if (lane == 0) actv[j] = p + bs[j];
  }
  __syncthreads();

  // each lane owns i-range [lane*2, lane*2+2) of the 128-wide hidden dim
  const float a0 = actv[lane * 2], a1 = actv[lane * 2 + 1];
  #pragma unroll
  for (int r = 0; r < 3; ++r) {
    const int k = wave + 4 * r;              // 0..11
    const int kk = (k < NOP) ? k : k - NOP;  // row in Wg/Wb
    const float* W = ((k < NOP) ? Wg : Wb) + kk * NH;
    float p = a0 * W[lane * 2] + a1 * W[lane * 2 + 1];
    #pragma unroll
    for (int off = 32; off; off >>= 1) p += __shfl_xor(p, off);
    if (lane == 0) {
      const float bias = (k < NOP) ? bg[kk] : bb[kk];
      coefs[b * 12 + k] = (p + bias) * Wr[kk];
    }
  }
  if (b == 0 && tid == 0) {
    float s = 0.f;
    #pragma unroll
    for (int k = 0; k < NOP; ++k) s += Wr[k];
    coefs[48] = s;
    coefs[49] = br[0];
  }
}

__global__ __launch_bounds__(256) void apply_kernel(
    const float* __restrict__ x, const float* __restrict__ sem,
    const float* __restrict__ coefs, float* __restrict__ out) {
  const int b = blockIdx.z;
  const int cbase = blockIdx.y * CCH;
  const int pix = (blockIdx.x * blockDim.x + threadIdx.x) * 4;

  const float* gk = coefs + b * 12;
  const float wrsum = coefs[48];
  const float brv = coefs[49];

  f4 scale = {wrsum, wrsum, wrsum, wrsum};
  f4 shift = {brv, brv, brv, brv};

  // sem planes 2..7 of input_semantics (B,8,H,W) — reused across C-chunks, L2-hot
  const float* semb = sem + ((size_t)b * 8 + 2) * HW + pix;
  #pragma unroll
  for (int k = 0; k < NOP; ++k) {
    const f4 s = *(const f4*)(semb + (size_t)k * HW);
    const float g = gk[k], be = gk[NOP + k];
    scale += g * s;
    shift += be * s;
  }

  const size_t base = ((size_t)b * NCH + cbase) * HW + pix;
  const float* xb = x + base;
  float* ob = out + base;
  #pragma unroll
  for (int c = 0; c < CCH; ++c) {
    // x read-once / out write-once: nontemporal to keep L2 for sem reuse
    const f4 v = __builtin_nontemporal_load((const f4*)(xb + (size_t)c * HW));
    const f4 r = v * scale + shift;
    __builtin_nontemporal_store(r, (f4*)(ob + (size_t)c * HW));
  }
}

extern "C" void kernel_launch(void* const* d_in, const int* in_sizes, int n_in,
                              void* d_out, int out_size, void* d_ws, size_t ws_size,
                              hipStream_t stream) {
  const float* x    = (const float*)d_in[0];
  const float* lang = (const float*)d_in[1];
  const float* sem  = (const float*)d_in[2];
  const float* Ws   = (const float*)d_in[3];
  const float* bs   = (const float*)d_in[4];
  const float* Wg   = (const float*)d_in[5];
  const float* bg   = (const float*)d_in[6];
  const float* Wb   = (const float*)d_in[7];
  const float* bb   = (const float*)d_in[8];
  const float* Wr   = (const float*)d_in[9];
  const float* br   = (const float*)d_in[10];
  float* out = (float*)d_out;
  float* coefs = (float*)d_ws;  // 50 floats

  coef_kernel<<<dim3(4), dim3(256), 0, stream>>>(lang, Ws, bs, Wg, bg, Wb, bb,
                                                 Wr, br, coefs);

  dim3 grid(HW / (256 * 4), NCH / CCH, 4);  // (16, 16, 4)
  apply_kernel<<<grid, dim3(256), 0, stream>>>(x, sem, coefs, out);
}